// Round 1
// baseline (814.163 us; speedup 1.0000x reference)
//
#include <hip/hip_runtime.h>
#include <math.h>

#define BSZ 32
#define NP  1024

// ---- workspace layout (float offsets) ----
#define OFF_ACC   0                         // acc[0]=sum(logR-S), [1]=sum S, [2]=sum T*logC, [3]=corr, [4]=chamfer
#define OFF_COS   8                         // dot[32], n1[32], n2[32]
#define OFF_POSE  104                       // 24 floats per batch
#define OFF_P1IN2 872
#define OFF_P2IN1 (OFF_P1IN2 + 3 * BSZ * NP)      // +98304
#define OFF_COLP  (OFF_P2IN1 + 3 * BSZ * NP)      // +98304 ; colPart = 32*32*4096 floats (16 MB)

// ---------------- pose + accumulator zeroing ----------------
__global__ void k_pose(const float* __restrict__ scale,
                       const float* __restrict__ rot,
                       const float* __restrict__ tr,
                       float* __restrict__ ws) {
    int t = threadIdx.x;                 // 64 threads
    if (t < 52) {                        // zero acc[8] + cosacc[96]
        ws[OFF_ACC + 2 * t]     = 0.f;
        ws[OFF_ACC + 2 * t + 1] = 0.f;
    }
    if (t >= BSZ) return;
    int b = t;
    float s = scale[b];
    float M[9];
#pragma unroll
    for (int i = 0; i < 9; ++i) M[i] = rot[b * 9 + i] * s;
    float t0 = tr[b * 3 + 0], t1 = tr[b * 3 + 1], t2 = tr[b * 3 + 2];
    float det = M[0] * (M[4] * M[8] - M[5] * M[7])
              - M[1] * (M[3] * M[8] - M[5] * M[6])
              + M[2] * (M[3] * M[7] - M[4] * M[6]);
    float id = 1.0f / det;
    float inv[9];
    inv[0] =  (M[4] * M[8] - M[5] * M[7]) * id;
    inv[1] = -(M[1] * M[8] - M[2] * M[7]) * id;
    inv[2] =  (M[1] * M[5] - M[2] * M[4]) * id;
    inv[3] = -(M[3] * M[8] - M[5] * M[6]) * id;
    inv[4] =  (M[0] * M[8] - M[2] * M[6]) * id;
    inv[5] = -(M[0] * M[5] - M[2] * M[3]) * id;
    inv[6] =  (M[3] * M[7] - M[4] * M[6]) * id;
    inv[7] = -(M[0] * M[7] - M[1] * M[6]) * id;
    inv[8] =  (M[0] * M[4] - M[1] * M[3]) * id;
    float u0 = -(inv[0] * t0 + inv[1] * t1 + inv[2] * t2);
    float u1 = -(inv[3] * t0 + inv[4] * t1 + inv[5] * t2);
    float u2 = -(inv[6] * t0 + inv[7] * t1 + inv[8] * t2);
    float* P = ws + OFF_POSE + b * 24;
#pragma unroll
    for (int i = 0; i < 9; ++i) P[i] = M[i];
    P[9] = t0; P[10] = t1; P[11] = t2;
#pragma unroll
    for (int i = 0; i < 9; ++i) P[12 + i] = inv[i];
    P[21] = u0; P[22] = u1; P[23] = u2;
}

// ---------------- fused pass over both assign matrices ----------------
// grid: 32 batches * 32 rowblocks = 1024 blocks, 256 threads (4 waves, 8 rows/wave)
__global__ __launch_bounds__(256, 3) void k_big(
    const float* __restrict__ am1, const float* __restrict__ am2,
    const float* __restrict__ pts1, const float* __restrict__ pts2,
    float* __restrict__ p1in2, float* __restrict__ p2in1,
    float* __restrict__ colPart, float* __restrict__ cosacc, float* __restrict__ acc) {
    __shared__ float cacc[4096];     // [4 arrays][1024 cols] block-level partials
    const int b  = blockIdx.x >> 5;
    const int rb = blockIdx.x & 31;
    const int wv = threadIdx.x >> 6;
    const int ln = threadIdx.x & 63;
    const int row0 = rb * 32 + wv * 8;

    for (int i = threadIdx.x; i < 4096; i += 256) cacc[i] = 0.f;
    __syncthreads();

    // lane's 16 fixed columns: c = 256*j + 4*ln + k  (i = 4*j + k)
    float pA[16][3];   // points_2 at lane's columns (for sa1 @ points_2)
    float pB[16][3];   // points_1 at lane's columns (for sa2 @ points_1)
#pragma unroll
    for (int j = 0; j < 4; ++j)
#pragma unroll
        for (int k = 0; k < 4; ++k) {
            int c = 256 * j + 4 * ln + k;
            int i = 4 * j + k;
            pA[i][0] = pts2[(b * NP + c) * 3 + 0];
            pA[i][1] = pts2[(b * NP + c) * 3 + 1];
            pA[i][2] = pts2[(b * NP + c) * 3 + 2];
            pB[i][0] = pts1[(b * NP + c) * 3 + 0];
            pB[i][1] = pts1[(b * NP + c) * 3 + 1];
            pB[i][2] = pts1[(b * NP + c) * 3 + 2];
        }

    float C1[16], T1[16], C2[16], T2[16];
#pragma unroll
    for (int i = 0; i < 16; ++i) { C1[i] = 0.f; T1[i] = 0.f; C2[i] = 0.f; T2[i] = 0.f; }
    float dacc = 0.f, n1a = 0.f, n2a = 0.f, e2a = 0.f, sSa = 0.f;

    const float4* rA = (const float4*)(am1 + ((size_t)b * NP + row0) * NP);
    const float4* rB = (const float4*)(am2 + ((size_t)b * NP + row0) * NP);

#pragma unroll 1
    for (int r = 0; r < 8; ++r) {
        float4 a[4], c4[4];
#pragma unroll
        for (int j = 0; j < 4; ++j) {
            a[j]  = rA[(size_t)r * 256 + ln + 64 * j];
            c4[j] = rB[(size_t)r * 256 + ln + 64 * j];
        }
        // cos-loss partials (need both raw matrices)
#pragma unroll
        for (int j = 0; j < 4; ++j) {
            dacc += a[j].x * c4[j].x + a[j].y * c4[j].y + a[j].z * c4[j].z + a[j].w * c4[j].w;
            n1a  += a[j].x * a[j].x + a[j].y * a[j].y + a[j].z * a[j].z + a[j].w * a[j].w;
            n2a  += c4[j].x * c4[j].x + c4[j].y * c4[j].y + c4[j].z * c4[j].z + c4[j].w * c4[j].w;
        }
        // ---- matrix 1 ----
        {
            float R = 0.f, Su = 0.f, q0 = 0.f, q1 = 0.f, q2 = 0.f;
#pragma unroll
            for (int j = 0; j < 4; ++j) {
                float* e = (float*)&a[j];
#pragma unroll
                for (int k = 0; k < 4; ++k) {
                    int i = 4 * j + k;
                    float v  = e[k];
                    float ex = __expf(v);
                    R += ex; Su += ex * v;
                    q0 += ex * pA[i][0]; q1 += ex * pA[i][1]; q2 += ex * pA[i][2];
                    C1[i] += ex;
                    e[k] = ex;
                }
            }
#pragma unroll
            for (int m = 1; m < 64; m <<= 1) {
                R  += __shfl_xor(R, m);  Su += __shfl_xor(Su, m);
                q0 += __shfl_xor(q0, m); q1 += __shfl_xor(q1, m); q2 += __shfl_xor(q2, m);
            }
            float inv = 1.0f / R;
#pragma unroll
            for (int j = 0; j < 4; ++j) {
                float* e = (float*)&a[j];
#pragma unroll
                for (int k = 0; k < 4; ++k) T1[4 * j + k] += e[k] * inv;
            }
            float S = Su * inv;
            if (ln == 0) {
                e2a += __logf(R) - S;
                sSa += S;
                int row = b * NP + row0 + r;
                p1in2[row * 3 + 0] = q0 * inv;
                p1in2[row * 3 + 1] = q1 * inv;
                p1in2[row * 3 + 2] = q2 * inv;
            }
        }
        // ---- matrix 2 ----
        {
            float R = 0.f, Su = 0.f, q0 = 0.f, q1 = 0.f, q2 = 0.f;
#pragma unroll
            for (int j = 0; j < 4; ++j) {
                float* e = (float*)&c4[j];
#pragma unroll
                for (int k = 0; k < 4; ++k) {
                    int i = 4 * j + k;
                    float v  = e[k];
                    float ex = __expf(v);
                    R += ex; Su += ex * v;
                    q0 += ex * pB[i][0]; q1 += ex * pB[i][1]; q2 += ex * pB[i][2];
                    C2[i] += ex;
                    e[k] = ex;
                }
            }
#pragma unroll
            for (int m = 1; m < 64; m <<= 1) {
                R  += __shfl_xor(R, m);  Su += __shfl_xor(Su, m);
                q0 += __shfl_xor(q0, m); q1 += __shfl_xor(q1, m); q2 += __shfl_xor(q2, m);
            }
            float inv = 1.0f / R;
#pragma unroll
            for (int j = 0; j < 4; ++j) {
                float* e = (float*)&c4[j];
#pragma unroll
                for (int k = 0; k < 4; ++k) T2[4 * j + k] += e[k] * inv;
            }
            float S = Su * inv;
            if (ln == 0) {
                e2a += __logf(R) - S;
                sSa += S;
                int row = b * NP + row0 + r;
                p2in1[row * 3 + 0] = q0 * inv;
                p2in1[row * 3 + 1] = q1 * inv;
                p2in1[row * 3 + 2] = q2 * inv;
            }
        }
    }

    // column partials -> LDS (only 4-wave contention per address; no global atomics)
#pragma unroll
    for (int j = 0; j < 4; ++j)
#pragma unroll
        for (int k = 0; k < 4; ++k) {
            int i = 4 * j + k;
            int c = 256 * j + 4 * ln + k;
            atomicAdd(&cacc[c],        C1[i]);
            atomicAdd(&cacc[1024 + c], T1[i]);
            atomicAdd(&cacc[2048 + c], C2[i]);
            atomicAdd(&cacc[3072 + c], T2[i]);
        }
#pragma unroll
    for (int m = 1; m < 64; m <<= 1) {
        dacc += __shfl_xor(dacc, m);
        n1a  += __shfl_xor(n1a, m);
        n2a  += __shfl_xor(n2a, m);
    }
    if (ln == 0) {
        atomicAdd(&cosacc[b], dacc);
        atomicAdd(&cosacc[32 + b], n1a);
        atomicAdd(&cosacc[64 + b], n2a);
        atomicAdd(&acc[0], e2a);
        atomicAdd(&acc[1], sSa);
    }
    __syncthreads();
    // stream block partials (plain coalesced stores)
    float4* cp = (float4*)(colPart + (size_t)blockIdx.x * 4096);
    const float4* cs = (const float4*)cacc;
    for (int i = threadIdx.x; i < 1024; i += 256) cp[i] = cs[i];
}

// ---------------- reduce column partials: sum T * log C ----------------
__global__ void k_colred(const float* __restrict__ colPart, float* __restrict__ acc) {
    int idx = blockIdx.x * 256 + threadIdx.x;   // 65536 = 32 b * 2 mats * 1024 cols
    int b = idx >> 11;
    int m = (idx >> 10) & 1;
    int c = idx & 1023;
    const float* p = colPart + (size_t)b * 32 * 4096 + m * 2048 + c;
    float C = 0.f, T = 0.f;
#pragma unroll
    for (int rbi = 0; rbi < 32; ++rbi) {
        C += p[rbi * 4096];
        T += p[rbi * 4096 + 1024];
    }
    float v = T * __logf(C);
#pragma unroll
    for (int mm = 1; mm < 64; mm <<= 1) v += __shfl_xor(v, mm);
    if ((threadIdx.x & 63) == 0) atomicAdd(&acc[2], v);
}

// ---------------- chamfer + Huber corr, transforms on the fly ----------------
// grid: pair(2) * dir(2) * b(32) * chunk(4) = 512 blocks, 256 threads, 1 X point/thread
__global__ __launch_bounds__(256) void k_cham(
    const float* __restrict__ p1, const float* __restrict__ p2,
    const float* __restrict__ p1in2, const float* __restrict__ p2in1,
    const float* __restrict__ pose, float* __restrict__ acc) {
    __shared__ float4 ys[NP];
    const int blk   = blockIdx.x;
    const int chunk = blk & 3;
    const int b     = (blk >> 2) & 31;
    const int dir   = (blk >> 7) & 1;
    const int pair  = blk >> 8;
    const float* P   = pose + b * 24 + pair * 12;   // fwd pose for pair0, inverse for pair1
    const float* raw = pair ? p2 : p1;
    const float* inA = pair ? p2in1 : p1in2;
    const int t = threadIdx.x;

    float m0 = P[0], m1 = P[1], m2 = P[2];
    float m3 = P[3], m4 = P[4], m5 = P[5];
    float m6 = P[6], m7 = P[7], m8 = P[8];
    float t0 = P[9], t1 = P[10], t2 = P[11];

    // stage Y set (1024 points, with |y|^2) into LDS
#pragma unroll
    for (int i = 0; i < 4; ++i) {
        int q = t + 256 * i;
        int gi = (b * NP + q) * 3;
        float x, y, z;
        if (dir == 0) { x = inA[gi]; y = inA[gi + 1]; z = inA[gi + 2]; }
        else {
            float rx = raw[gi], ry = raw[gi + 1], rz = raw[gi + 2];
            x = m0 * rx + m1 * ry + m2 * rz + t0;
            y = m3 * rx + m4 * ry + m5 * rz + t1;
            z = m6 * rx + m7 * ry + m8 * rz + t2;
        }
        ys[q] = make_float4(x, y, z, x * x + y * y + z * z);
    }
    __syncthreads();

    // this thread's X point
    int xi = chunk * 256 + t;
    int gx = (b * NP + xi) * 3;
    float x0, x1, x2;
    if (dir == 0) {
        float rx = raw[gx], ry = raw[gx + 1], rz = raw[gx + 2];
        x0 = m0 * rx + m1 * ry + m2 * rz + t0;
        x1 = m3 * rx + m4 * ry + m5 * rz + t1;
        x2 = m6 * rx + m7 * ry + m8 * rz + t2;
    } else { x0 = inA[gx]; x1 = inA[gx + 1]; x2 = inA[gx + 2]; }
    float sx = x0 * x0 + x1 * x1 + x2 * x2;

    float mn = 3.0e38f;
#pragma unroll 4
    for (int o = 0; o < NP; ++o) {
        float4 yv = ys[o];   // broadcast read, conflict-free
        float d = fmaf(-2.0f, x0 * yv.x + x1 * yv.y + x2 * yv.z, sx + yv.w);
        mn = fminf(mn, d);
    }
    mn = fmaxf(mn, 0.0f);    // clamp commutes with min

    float v = mn;
#pragma unroll
    for (int m = 1; m < 64; m <<= 1) v += __shfl_xor(v, m);
    if ((t & 63) == 0) atomicAdd(&acc[4], v);

    if (dir == 0) {          // Huber corr: A = inA (ys), P-set = transformed X
        float4 a = ys[xi];
        float s = 0.f;
        float d0 = fabsf(a.x - x0); s += (d0 > 0.1f) ? (d0 - 0.05f) : (d0 * d0 * 5.0f);
        float d1 = fabsf(a.y - x1); s += (d1 > 0.1f) ? (d1 - 0.05f) : (d1 * d1 * 5.0f);
        float d2 = fabsf(a.z - x2); s += (d2 > 0.1f) ? (d2 - 0.05f) : (d2 * d2 * 5.0f);
#pragma unroll
        for (int m = 1; m < 64; m <<= 1) s += __shfl_xor(s, m);
        if ((t & 63) == 0) atomicAdd(&acc[3], s);
    }
}

// ---------------- finalize ----------------
__global__ void k_final(const float* __restrict__ acc, const float* __restrict__ cosacc,
                        float* __restrict__ out) {
    if (threadIdx.x != 0) return;
    const float invBN = 1.0f / 32768.0f;
    float ent2 = 1e-4f * acc[0] * invBN;
    float ent1 = 1e-4f * (acc[2] - acc[1]) * invBN;
    float corr = acc[3] * invBN;
    float cham = acc[4] * invBN;
    float cosl = 0.f;
    for (int b = 0; b < 32; ++b) {
        float dot = cosacc[b];
        float na = fmaxf(sqrtf(cosacc[32 + b]), 1e-8f);
        float nb = fmaxf(sqrtf(cosacc[64 + b]), 1e-8f);
        cosl += 1.0f - dot / (na * nb);
    }
    cosl *= (1.0f / 32.0f);
    out[0] = cham + corr + ent2 + ent1 + cosl;
}

extern "C" void kernel_launch(void* const* d_in, const int* in_sizes, int n_in,
                              void* d_out, int out_size, void* d_ws, size_t ws_size,
                              hipStream_t stream) {
    const float* p1    = (const float*)d_in[0];
    const float* p2    = (const float*)d_in[1];
    const float* am1   = (const float*)d_in[2];
    const float* am2   = (const float*)d_in[3];
    const float* scale = (const float*)d_in[4];
    const float* rot   = (const float*)d_in[5];
    const float* tr    = (const float*)d_in[6];

    float* ws = (float*)d_ws;
    float* acc     = ws + OFF_ACC;
    float* cosacc  = ws + OFF_COS;
    float* pose    = ws + OFF_POSE;
    float* p1in2   = ws + OFF_P1IN2;
    float* p2in1   = ws + OFF_P2IN1;
    float* colPart = ws + OFF_COLP;

    k_pose<<<1, 64, 0, stream>>>(scale, rot, tr, ws);
    k_big<<<1024, 256, 0, stream>>>(am1, am2, p1, p2, p1in2, p2in1,
                                    colPart, cosacc, acc);
    k_colred<<<256, 256, 0, stream>>>(colPart, acc);
    k_cham<<<512, 256, 0, stream>>>(p1, p2, p1in2, p2in1, pose, acc);
    k_final<<<1, 64, 0, stream>>>(acc, cosacc, (float*)d_out);
}

// Round 2
// 547.413 us; speedup vs baseline: 1.4873x; 1.4873x over previous
//
#include <hip/hip_runtime.h>
#include <math.h>

#define BSZ 32
#define NP  1024

// ---- workspace layout (float offsets) ----
#define OFF_ACC   0                         // acc[0]=sum(logR-S), [1]=sum S, [2]=sum T*logC, [3]=corr, [4]=chamfer
#define OFF_COS   8                         // dot[32], n1[32], n2[32]
#define OFF_POSE  104                       // 24 floats per batch
#define OFF_P1IN2 872
#define OFF_P2IN1 (OFF_P1IN2 + 3 * BSZ * NP)      // +98304
#define OFF_COLP  (OFF_P2IN1 + 3 * BSZ * NP)      // +98304 ; colPart = 1024 blocks * 4096 floats (16.8 MB)

// ---------------- pose + accumulator zeroing ----------------
__global__ void k_pose(const float* __restrict__ scale,
                       const float* __restrict__ rot,
                       const float* __restrict__ tr,
                       float* __restrict__ ws) {
    int t = threadIdx.x;                 // 64 threads
    if (t < 52) {                        // zero acc[8] + cosacc[96]
        ws[OFF_ACC + 2 * t]     = 0.f;
        ws[OFF_ACC + 2 * t + 1] = 0.f;
    }
    if (t >= BSZ) return;
    int b = t;
    float s = scale[b];
    float M[9];
#pragma unroll
    for (int i = 0; i < 9; ++i) M[i] = rot[b * 9 + i] * s;
    float t0 = tr[b * 3 + 0], t1 = tr[b * 3 + 1], t2 = tr[b * 3 + 2];
    float det = M[0] * (M[4] * M[8] - M[5] * M[7])
              - M[1] * (M[3] * M[8] - M[5] * M[6])
              + M[2] * (M[3] * M[7] - M[4] * M[6]);
    float id = 1.0f / det;
    float inv[9];
    inv[0] =  (M[4] * M[8] - M[5] * M[7]) * id;
    inv[1] = -(M[1] * M[8] - M[2] * M[7]) * id;
    inv[2] =  (M[1] * M[5] - M[2] * M[4]) * id;
    inv[3] = -(M[3] * M[8] - M[5] * M[6]) * id;
    inv[4] =  (M[0] * M[8] - M[2] * M[6]) * id;
    inv[5] = -(M[0] * M[5] - M[2] * M[3]) * id;
    inv[6] =  (M[3] * M[7] - M[4] * M[6]) * id;
    inv[7] = -(M[0] * M[7] - M[1] * M[6]) * id;
    inv[8] =  (M[0] * M[4] - M[1] * M[3]) * id;
    float u0 = -(inv[0] * t0 + inv[1] * t1 + inv[2] * t2);
    float u1 = -(inv[3] * t0 + inv[4] * t1 + inv[5] * t2);
    float u2 = -(inv[6] * t0 + inv[7] * t1 + inv[8] * t2);
    float* P = ws + OFF_POSE + b * 24;
#pragma unroll
    for (int i = 0; i < 9; ++i) P[i] = M[i];
    P[9] = t0; P[10] = t1; P[11] = t2;
#pragma unroll
    for (int i = 0; i < 9; ++i) P[12 + i] = inv[i];
    P[21] = u0; P[22] = u1; P[23] = u2;
}

// ---------------- fused pass over both assign matrices ----------------
// grid: 32 batches * 32 rowblocks = 1024 blocks, 256 threads (4 waves, 8 rows/wave)
// Points live in LDS (shared by all 4 waves), SoA with k-major permutation so the
// inner-loop reads are bank-conflict-free:  idx(c) = 256*(c&3) + (c>>2)
//   -> for fixed (j,k) the 64 lanes read banks ln%32 (2-way aliasing = free).
__global__ __launch_bounds__(256) void k_big(
    const float* __restrict__ am1, const float* __restrict__ am2,
    const float* __restrict__ pts1, const float* __restrict__ pts2,
    float* __restrict__ p1in2, float* __restrict__ p2in1,
    float* __restrict__ colPart, float* __restrict__ cosacc, float* __restrict__ acc) {
    __shared__ float cacc[4096];     // [4 arrays][1024 cols] block-level partials
    __shared__ float ptsL[6144];     // [mat][dim][ idx(c) ]  mat0=pts2(pA), mat1=pts1(pB)
    const int b  = blockIdx.x >> 5;
    const int rb = blockIdx.x & 31;
    const int wv = threadIdx.x >> 6;
    const int ln = threadIdx.x & 63;
    const int row0 = rb * 32 + wv * 8;

    for (int i = threadIdx.x; i < 4096; i += 256) cacc[i] = 0.f;
    // stage points: coalesced global read, permuted LDS write (one-time)
    for (int t = threadIdx.x; t < 6144; t += 256) {
        int mat = t >= 3072;
        int loc = t - mat * 3072;          // 0..3071 = c*3+d
        int c = loc / 3, d = loc - 3 * c;
        float v = mat ? pts1[b * 3072 + loc] : pts2[b * 3072 + loc];
        ptsL[mat * 3072 + d * 1024 + 256 * (c & 3) + (c >> 2)] = v;
    }
    __syncthreads();

    float C1[16], T1[16], C2[16], T2[16];
#pragma unroll
    for (int i = 0; i < 16; ++i) { C1[i] = 0.f; T1[i] = 0.f; C2[i] = 0.f; T2[i] = 0.f; }
    float dacc = 0.f, n1a = 0.f, n2a = 0.f, e2a = 0.f, sSa = 0.f;

    const float4* rA = (const float4*)(am1 + ((size_t)b * NP + row0) * NP);
    const float4* rB = (const float4*)(am2 + ((size_t)b * NP + row0) * NP);

#pragma unroll 1
    for (int r = 0; r < 8; ++r) {
        float4 a[4], c4[4];
#pragma unroll
        for (int j = 0; j < 4; ++j) {
            a[j]  = rA[(size_t)r * 256 + ln + 64 * j];
            c4[j] = rB[(size_t)r * 256 + ln + 64 * j];
        }
        // cos-loss partials (need both raw matrices)
#pragma unroll
        for (int j = 0; j < 4; ++j) {
            dacc += a[j].x * c4[j].x + a[j].y * c4[j].y + a[j].z * c4[j].z + a[j].w * c4[j].w;
            n1a  += a[j].x * a[j].x + a[j].y * a[j].y + a[j].z * a[j].z + a[j].w * a[j].w;
            n2a  += c4[j].x * c4[j].x + c4[j].y * c4[j].y + c4[j].z * c4[j].z + c4[j].w * c4[j].w;
        }
        // ---- matrix 1 (softmax over am1 row, weights * pts2) ----
        {
            float R = 0.f, Su = 0.f, q0 = 0.f, q1 = 0.f, q2 = 0.f;
#pragma unroll
            for (int j = 0; j < 4; ++j) {
                float* e = (float*)&a[j];
#pragma unroll
                for (int k = 0; k < 4; ++k) {
                    int i = 4 * j + k;
                    int pidx = 256 * k + 64 * j + ln;
                    float v  = e[k];
                    float ex = __expf(v);
                    R += ex; Su += ex * v;
                    q0 += ex * ptsL[pidx];
                    q1 += ex * ptsL[1024 + pidx];
                    q2 += ex * ptsL[2048 + pidx];
                    C1[i] += ex;
                    e[k] = ex;
                }
            }
#pragma unroll
            for (int m = 1; m < 64; m <<= 1) {
                R  += __shfl_xor(R, m);  Su += __shfl_xor(Su, m);
                q0 += __shfl_xor(q0, m); q1 += __shfl_xor(q1, m); q2 += __shfl_xor(q2, m);
            }
            float inv = 1.0f / R;
#pragma unroll
            for (int j = 0; j < 4; ++j) {
                float* e = (float*)&a[j];
#pragma unroll
                for (int k = 0; k < 4; ++k) T1[4 * j + k] += e[k] * inv;
            }
            float S = Su * inv;
            if (ln == 0) {
                e2a += __logf(R) - S;
                sSa += S;
                int row = b * NP + row0 + r;
                p1in2[row * 3 + 0] = q0 * inv;
                p1in2[row * 3 + 1] = q1 * inv;
                p1in2[row * 3 + 2] = q2 * inv;
            }
        }
        // ---- matrix 2 (softmax over am2 row, weights * pts1) ----
        {
            float R = 0.f, Su = 0.f, q0 = 0.f, q1 = 0.f, q2 = 0.f;
#pragma unroll
            for (int j = 0; j < 4; ++j) {
                float* e = (float*)&c4[j];
#pragma unroll
                for (int k = 0; k < 4; ++k) {
                    int i = 4 * j + k;
                    int pidx = 3072 + 256 * k + 64 * j + ln;
                    float v  = e[k];
                    float ex = __expf(v);
                    R += ex; Su += ex * v;
                    q0 += ex * ptsL[pidx];
                    q1 += ex * ptsL[1024 + pidx];
                    q2 += ex * ptsL[2048 + pidx];
                    C2[i] += ex;
                    e[k] = ex;
                }
            }
#pragma unroll
            for (int m = 1; m < 64; m <<= 1) {
                R  += __shfl_xor(R, m);  Su += __shfl_xor(Su, m);
                q0 += __shfl_xor(q0, m); q1 += __shfl_xor(q1, m); q2 += __shfl_xor(q2, m);
            }
            float inv = 1.0f / R;
#pragma unroll
            for (int j = 0; j < 4; ++j) {
                float* e = (float*)&c4[j];
#pragma unroll
                for (int k = 0; k < 4; ++k) T2[4 * j + k] += e[k] * inv;
            }
            float S = Su * inv;
            if (ln == 0) {
                e2a += __logf(R) - S;
                sSa += S;
                int row = b * NP + row0 + r;
                p2in1[row * 3 + 0] = q0 * inv;
                p2in1[row * 3 + 1] = q1 * inv;
                p2in1[row * 3 + 2] = q2 * inv;
            }
        }
    }

    // column partials -> LDS (4-wave contention max; no global atomics)
#pragma unroll
    for (int j = 0; j < 4; ++j)
#pragma unroll
        for (int k = 0; k < 4; ++k) {
            int i = 4 * j + k;
            int c = 256 * j + 4 * ln + k;
            atomicAdd(&cacc[c],        C1[i]);
            atomicAdd(&cacc[1024 + c], T1[i]);
            atomicAdd(&cacc[2048 + c], C2[i]);
            atomicAdd(&cacc[3072 + c], T2[i]);
        }
#pragma unroll
    for (int m = 1; m < 64; m <<= 1) {
        dacc += __shfl_xor(dacc, m);
        n1a  += __shfl_xor(n1a, m);
        n2a  += __shfl_xor(n2a, m);
    }
    if (ln == 0) {
        atomicAdd(&cosacc[b], dacc);
        atomicAdd(&cosacc[32 + b], n1a);
        atomicAdd(&cosacc[64 + b], n2a);
        atomicAdd(&acc[0], e2a);
        atomicAdd(&acc[1], sSa);
    }
    __syncthreads();
    // stream block partials (plain coalesced stores)
    float4* cp = (float4*)(colPart + (size_t)blockIdx.x * 4096);
    const float4* cs = (const float4*)cacc;
    for (int i = threadIdx.x; i < 1024; i += 256) cp[i] = cs[i];
}

// ---------------- reduce column partials: sum T * log C ----------------
__global__ void k_colred(const float* __restrict__ colPart, float* __restrict__ acc) {
    int idx = blockIdx.x * 256 + threadIdx.x;   // 65536 = 32 b * 2 mats * 1024 cols
    int b = idx >> 11;
    int m = (idx >> 10) & 1;
    int c = idx & 1023;
    const float* p = colPart + (size_t)b * 32 * 4096 + m * 2048 + c;
    float C = 0.f, T = 0.f;
#pragma unroll
    for (int rbi = 0; rbi < 32; ++rbi) {
        C += p[rbi * 4096];
        T += p[rbi * 4096 + 1024];
    }
    float v = T * __logf(C);
#pragma unroll
    for (int mm = 1; mm < 64; mm <<= 1) v += __shfl_xor(v, mm);
    if ((threadIdx.x & 63) == 0) atomicAdd(&acc[2], v);
}

// ---------------- chamfer + Huber corr, transforms on the fly ----------------
// grid: pair(2) * dir(2) * b(32) * chunk(4) = 512 blocks, 256 threads, 1 X point/thread
__global__ __launch_bounds__(256) void k_cham(
    const float* __restrict__ p1, const float* __restrict__ p2,
    const float* __restrict__ p1in2, const float* __restrict__ p2in1,
    const float* __restrict__ pose, float* __restrict__ acc) {
    __shared__ float4 ys[NP];
    const int blk   = blockIdx.x;
    const int chunk = blk & 3;
    const int b     = (blk >> 2) & 31;
    const int dir   = (blk >> 7) & 1;
    const int pair  = blk >> 8;
    const float* P   = pose + b * 24 + pair * 12;   // fwd pose for pair0, inverse for pair1
    const float* raw = pair ? p2 : p1;
    const float* inA = pair ? p2in1 : p1in2;
    const int t = threadIdx.x;

    float m0 = P[0], m1 = P[1], m2 = P[2];
    float m3 = P[3], m4 = P[4], m5 = P[5];
    float m6 = P[6], m7 = P[7], m8 = P[8];
    float t0 = P[9], t1 = P[10], t2 = P[11];

    // stage Y set (1024 points, with |y|^2) into LDS
#pragma unroll
    for (int i = 0; i < 4; ++i) {
        int q = t + 256 * i;
        int gi = (b * NP + q) * 3;
        float x, y, z;
        if (dir == 0) { x = inA[gi]; y = inA[gi + 1]; z = inA[gi + 2]; }
        else {
            float rx = raw[gi], ry = raw[gi + 1], rz = raw[gi + 2];
            x = m0 * rx + m1 * ry + m2 * rz + t0;
            y = m3 * rx + m4 * ry + m5 * rz + t1;
            z = m6 * rx + m7 * ry + m8 * rz + t2;
        }
        ys[q] = make_float4(x, y, z, x * x + y * y + z * z);
    }
    __syncthreads();

    // this thread's X point
    int xi = chunk * 256 + t;
    int gx = (b * NP + xi) * 3;
    float x0, x1, x2;
    if (dir == 0) {
        float rx = raw[gx], ry = raw[gx + 1], rz = raw[gx + 2];
        x0 = m0 * rx + m1 * ry + m2 * rz + t0;
        x1 = m3 * rx + m4 * ry + m5 * rz + t1;
        x2 = m6 * rx + m7 * ry + m8 * rz + t2;
    } else { x0 = inA[gx]; x1 = inA[gx + 1]; x2 = inA[gx + 2]; }
    float sx = x0 * x0 + x1 * x1 + x2 * x2;

    float mn = 3.0e38f;
#pragma unroll 4
    for (int o = 0; o < NP; ++o) {
        float4 yv = ys[o];   // broadcast read, conflict-free
        float d = fmaf(-2.0f, x0 * yv.x + x1 * yv.y + x2 * yv.z, sx + yv.w);
        mn = fminf(mn, d);
    }
    mn = fmaxf(mn, 0.0f);    // clamp commutes with min

    float v = mn;
#pragma unroll
    for (int m = 1; m < 64; m <<= 1) v += __shfl_xor(v, m);
    if ((t & 63) == 0) atomicAdd(&acc[4], v);

    if (dir == 0) {          // Huber corr: A = inA (ys), P-set = transformed X
        float4 a = ys[xi];
        float s = 0.f;
        float d0 = fabsf(a.x - x0); s += (d0 > 0.1f) ? (d0 - 0.05f) : (d0 * d0 * 5.0f);
        float d1 = fabsf(a.y - x1); s += (d1 > 0.1f) ? (d1 - 0.05f) : (d1 * d1 * 5.0f);
        float d2 = fabsf(a.z - x2); s += (d2 > 0.1f) ? (d2 - 0.05f) : (d2 * d2 * 5.0f);
#pragma unroll
        for (int m = 1; m < 64; m <<= 1) s += __shfl_xor(s, m);
        if ((t & 63) == 0) atomicAdd(&acc[3], s);
    }
}

// ---------------- finalize ----------------
__global__ void k_final(const float* __restrict__ acc, const float* __restrict__ cosacc,
                        float* __restrict__ out) {
    if (threadIdx.x != 0) return;
    const float invBN = 1.0f / 32768.0f;
    float ent2 = 1e-4f * acc[0] * invBN;
    float ent1 = 1e-4f * (acc[2] - acc[1]) * invBN;
    float corr = acc[3] * invBN;
    float cham = acc[4] * invBN;
    float cosl = 0.f;
    for (int b = 0; b < 32; ++b) {
        float dot = cosacc[b];
        float na = fmaxf(sqrtf(cosacc[32 + b]), 1e-8f);
        float nb = fmaxf(sqrtf(cosacc[64 + b]), 1e-8f);
        cosl += 1.0f - dot / (na * nb);
    }
    cosl *= (1.0f / 32.0f);
    out[0] = cham + corr + ent2 + ent1 + cosl;
}

extern "C" void kernel_launch(void* const* d_in, const int* in_sizes, int n_in,
                              void* d_out, int out_size, void* d_ws, size_t ws_size,
                              hipStream_t stream) {
    const float* p1    = (const float*)d_in[0];
    const float* p2    = (const float*)d_in[1];
    const float* am1   = (const float*)d_in[2];
    const float* am2   = (const float*)d_in[3];
    const float* scale = (const float*)d_in[4];
    const float* rot   = (const float*)d_in[5];
    const float* tr    = (const float*)d_in[6];

    float* ws = (float*)d_ws;
    float* acc     = ws + OFF_ACC;
    float* cosacc  = ws + OFF_COS;
    float* pose    = ws + OFF_POSE;
    float* p1in2   = ws + OFF_P1IN2;
    float* p2in1   = ws + OFF_P2IN1;
    float* colPart = ws + OFF_COLP;

    k_pose<<<1, 64, 0, stream>>>(scale, rot, tr, ws);
    k_big<<<1024, 256, 0, stream>>>(am1, am2, p1, p2, p1in2, p2in1,
                                    colPart, cosacc, acc);
    k_colred<<<256, 256, 0, stream>>>(colPart, acc);
    k_cham<<<512, 256, 0, stream>>>(p1, p2, p1in2, p2in1, pose, acc);
    k_final<<<1, 64, 0, stream>>>(acc, cosacc, (float*)d_out);
}

// Round 3
// 470.895 us; speedup vs baseline: 1.7290x; 1.1625x over previous
//
#include <hip/hip_runtime.h>
#include <math.h>

#define BSZ 32
#define NP  1024

// ---- workspace layout (float offsets) ----
#define OFF_ACC   0                          // acc[0]=sum(logR-S), [1]=sum S, [2]=sum T*logC, [3]=corr, [4]=chamfer
#define OFF_COS   8                          // dot[32], n1[32], n2[32]
#define OFF_POSE  104                        // 24 floats per batch
#define OFF_P1IN2 872
#define OFF_P2IN1 (OFF_P1IN2 + 98304)
#define OFF_INVR  (OFF_P2IN1 + 98304)        // invR[2][32][1024] = 65536 floats
#define OFF_COLP  (OFF_INVR + 65536)         // colP[32][32][4][1024] = 4M floats (16 MB)

// ---------------- pose + accumulator zeroing ----------------
__global__ void k_pose(const float* __restrict__ scale,
                       const float* __restrict__ rot,
                       const float* __restrict__ tr,
                       float* __restrict__ ws) {
    int t = threadIdx.x;                 // 64 threads
    if (t < 52) {                        // zero acc[8] + cosacc[96]
        ws[OFF_ACC + 2 * t]     = 0.f;
        ws[OFF_ACC + 2 * t + 1] = 0.f;
    }
    if (t >= BSZ) return;
    int b = t;
    float s = scale[b];
    float M[9];
#pragma unroll
    for (int i = 0; i < 9; ++i) M[i] = rot[b * 9 + i] * s;
    float t0 = tr[b * 3 + 0], t1 = tr[b * 3 + 1], t2 = tr[b * 3 + 2];
    float det = M[0] * (M[4] * M[8] - M[5] * M[7])
              - M[1] * (M[3] * M[8] - M[5] * M[6])
              + M[2] * (M[3] * M[7] - M[4] * M[6]);
    float id = 1.0f / det;
    float inv[9];
    inv[0] =  (M[4] * M[8] - M[5] * M[7]) * id;
    inv[1] = -(M[1] * M[8] - M[2] * M[7]) * id;
    inv[2] =  (M[1] * M[5] - M[2] * M[4]) * id;
    inv[3] = -(M[3] * M[8] - M[5] * M[6]) * id;
    inv[4] =  (M[0] * M[8] - M[2] * M[6]) * id;
    inv[5] = -(M[0] * M[5] - M[2] * M[3]) * id;
    inv[6] =  (M[3] * M[7] - M[4] * M[6]) * id;
    inv[7] = -(M[0] * M[7] - M[1] * M[6]) * id;
    inv[8] =  (M[0] * M[4] - M[1] * M[3]) * id;
    float u0 = -(inv[0] * t0 + inv[1] * t1 + inv[2] * t2);
    float u1 = -(inv[3] * t0 + inv[4] * t1 + inv[5] * t2);
    float u2 = -(inv[6] * t0 + inv[7] * t1 + inv[8] * t2);
    float* P = ws + OFF_POSE + b * 24;
#pragma unroll
    for (int i = 0; i < 9; ++i) P[i] = M[i];
    P[9] = t0; P[10] = t1; P[11] = t2;
#pragma unroll
    for (int i = 0; i < 9; ++i) P[12 + i] = inv[i];
    P[21] = u0; P[22] = u1; P[23] = u2;
}

// ---------------- pass 1: per-row softmax stats, one matrix per block ----------------
// grid: 2048 = b(32) * m(2) * rb(32); 256 thr = 4 waves * 8 rows/wave.
// Points in registers (48 VGPR, one side only). No C/T, no LDS staging, no barriers
// in the hot loop -> low VGPR, high occupancy, pure stream.
__global__ __launch_bounds__(256) void k_rows(
    const float* __restrict__ am1, const float* __restrict__ am2,
    const float* __restrict__ pts1, const float* __restrict__ pts2,
    float* __restrict__ p1in2, float* __restrict__ p2in1,
    float* __restrict__ invR, float* __restrict__ acc) {
    __shared__ float sred[8];
    const int bid = blockIdx.x;
    const int rb = bid & 31;
    const int m  = (bid >> 5) & 1;
    const int b  = bid >> 6;
    const int wv = threadIdx.x >> 6, ln = threadIdx.x & 63;
    const int row0 = rb * 32 + wv * 8;
    const float* am  = m ? am2 : am1;
    const float* pts = m ? pts1 : pts2;     // mat1 pairs with points_2, mat2 with points_1
    float* pout   = m ? p2in1 : p1in2;
    float* invout = invR + (m * BSZ + b) * NP;

    // lane's 16 columns: c = 256*j + 4*ln + k
    float P[16][3];
#pragma unroll
    for (int j = 0; j < 4; ++j)
#pragma unroll
        for (int k = 0; k < 4; ++k) {
            int c = 256 * j + 4 * ln + k;
            const float* p = pts + ((size_t)b * NP + c) * 3;
            P[4 * j + k][0] = p[0];
            P[4 * j + k][1] = p[1];
            P[4 * j + k][2] = p[2];
        }

    float e2a = 0.f, sSa = 0.f;
    const float4* rA = (const float4*)(am + ((size_t)b * NP + row0) * NP);

#pragma unroll 1
    for (int r = 0; r < 8; ++r) {
        float4 a[4];
#pragma unroll
        for (int j = 0; j < 4; ++j) a[j] = rA[(size_t)r * 256 + ln + 64 * j];
        float R = 0.f, Su = 0.f, q0 = 0.f, q1 = 0.f, q2 = 0.f;
#pragma unroll
        for (int j = 0; j < 4; ++j) {
            float* e = (float*)&a[j];
#pragma unroll
            for (int k = 0; k < 4; ++k) {
                int i = 4 * j + k;
                float v  = e[k];
                float ex = __expf(v);
                R += ex; Su += ex * v;
                q0 += ex * P[i][0]; q1 += ex * P[i][1]; q2 += ex * P[i][2];
            }
        }
#pragma unroll
        for (int s = 1; s < 64; s <<= 1) {
            R  += __shfl_xor(R, s);  Su += __shfl_xor(Su, s);
            q0 += __shfl_xor(q0, s); q1 += __shfl_xor(q1, s); q2 += __shfl_xor(q2, s);
        }
        if (ln == 0) {
            float inv = 1.0f / R;
            float S = Su * inv;
            e2a += __logf(R) - S;
            sSa += S;
            int row = row0 + r;
            invout[row] = inv;
            float* o = pout + ((size_t)b * NP + row) * 3;
            o[0] = q0 * inv; o[1] = q1 * inv; o[2] = q2 * inv;
        }
    }
    if (ln == 0) { sred[wv] = e2a; sred[4 + wv] = sSa; }
    __syncthreads();
    if (threadIdx.x == 0) {
        atomicAdd(&acc[0], sred[0] + sred[1] + sred[2] + sred[3]);
        atomicAdd(&acc[1], sred[4] + sred[5] + sred[6] + sred[7]);
    }
}

// ---------------- pass 2: column sums (C,T) + cos partials, column-parallel ----------------
// grid: 1024 = b(32) * rt(32); block covers rows rt*32..+32 of BOTH matrices, all 1024 cols.
// Thread owns 4 cols (float4 loads, perfectly coalesced). C/T in 16 registers, no
// cross-lane work, no atomics except 3 per block. Matrices are L3-warm from pass 1.
__global__ __launch_bounds__(256) void k_cols2(
    const float* __restrict__ am1, const float* __restrict__ am2,
    const float* __restrict__ invR, float* __restrict__ colP,
    float* __restrict__ cosacc) {
    __shared__ float invL[64];     // [m][32 rows]
    __shared__ float cred[12];
    const int rt = blockIdx.x & 31;
    const int b  = blockIdx.x >> 5;
    const int t  = threadIdx.x;
    if (t < 64) {
        int mm = t >> 5, rr = t & 31;
        invL[t] = invR[(mm * BSZ + b) * NP + rt * 32 + rr];
    }
    __syncthreads();
    const float4* s1 = (const float4*)(am1 + ((size_t)b * NP + rt * 32) * NP) + t;
    const float4* s2 = (const float4*)(am2 + ((size_t)b * NP + rt * 32) * NP) + t;
    float C1x=0,C1y=0,C1z=0,C1w=0, T1x=0,T1y=0,T1z=0,T1w=0;
    float C2x=0,C2y=0,C2z=0,C2w=0, T2x=0,T2y=0,T2z=0,T2w=0;
    float dacc = 0.f, n1a = 0.f, n2a = 0.f;
#pragma unroll 4
    for (int r = 0; r < 32; ++r) {
        float4 v1 = s1[(size_t)r * 256];
        float4 v2 = s2[(size_t)r * 256];
        dacc += v1.x*v2.x + v1.y*v2.y + v1.z*v2.z + v1.w*v2.w;
        n1a  += v1.x*v1.x + v1.y*v1.y + v1.z*v1.z + v1.w*v1.w;
        n2a  += v2.x*v2.x + v2.y*v2.y + v2.z*v2.z + v2.w*v2.w;
        float w1 = invL[r], w2 = invL[32 + r];
        float e;
        e = __expf(v1.x); C1x += e; T1x += e * w1;
        e = __expf(v1.y); C1y += e; T1y += e * w1;
        e = __expf(v1.z); C1z += e; T1z += e * w1;
        e = __expf(v1.w); C1w += e; T1w += e * w1;
        e = __expf(v2.x); C2x += e; T2x += e * w2;
        e = __expf(v2.y); C2y += e; T2y += e * w2;
        e = __expf(v2.z); C2z += e; T2z += e * w2;
        e = __expf(v2.w); C2w += e; T2w += e * w2;
    }
    // colP layout: [b][rt][arr(0=C1,1=T1,2=C2,3=T2)][1024 cols]
    float4* cp = (float4*)colP + ((size_t)(b * 32 + rt)) * 1024 + t;
    cp[0]   = make_float4(C1x, C1y, C1z, C1w);
    cp[256] = make_float4(T1x, T1y, T1z, T1w);
    cp[512] = make_float4(C2x, C2y, C2z, C2w);
    cp[768] = make_float4(T2x, T2y, T2z, T2w);
#pragma unroll
    for (int s = 1; s < 64; s <<= 1) {
        dacc += __shfl_xor(dacc, s);
        n1a  += __shfl_xor(n1a, s);
        n2a  += __shfl_xor(n2a, s);
    }
    if ((t & 63) == 0) {
        int wv = t >> 6;
        cred[wv] = dacc; cred[4 + wv] = n1a; cred[8 + wv] = n2a;
    }
    __syncthreads();
    if (t == 0) {
        atomicAdd(&cosacc[b],      cred[0] + cred[1] + cred[2]  + cred[3]);
        atomicAdd(&cosacc[32 + b], cred[4] + cred[5] + cred[6]  + cred[7]);
        atomicAdd(&cosacc[64 + b], cred[8] + cred[9] + cred[10] + cred[11]);
    }
}

// ---------------- reduce column partials: sum T * log C ----------------
__global__ void k_colred2(const float* __restrict__ colP, float* __restrict__ acc) {
    int idx = blockIdx.x * 256 + threadIdx.x;   // 65536 = bm(64) * c(1024)
    int bm = idx >> 10;
    int c  = idx & 1023;
    int b = bm >> 1, m = bm & 1;
    const float* base = colP + (size_t)b * 32 * 4 * NP + (2 * m) * NP + c;
    float C = 0.f, T = 0.f;
#pragma unroll
    for (int rt = 0; rt < 32; ++rt) {
        C += base[(size_t)rt * 4 * NP];
        T += base[(size_t)rt * 4 * NP + NP];
    }
    float v = T * __logf(C);
#pragma unroll
    for (int s = 1; s < 64; s <<= 1) v += __shfl_xor(v, s);
    if ((threadIdx.x & 63) == 0) atomicAdd(&acc[2], v);
}

// ---------------- chamfer + Huber corr, transforms on the fly ----------------
// grid: pair(2) * dir(2) * b(32) * chunk(4) = 512 blocks, 256 threads, 1 X point/thread
__global__ __launch_bounds__(256) void k_cham(
    const float* __restrict__ p1, const float* __restrict__ p2,
    const float* __restrict__ p1in2, const float* __restrict__ p2in1,
    const float* __restrict__ pose, float* __restrict__ acc) {
    __shared__ float4 ys[NP];
    const int blk   = blockIdx.x;
    const int chunk = blk & 3;
    const int b     = (blk >> 2) & 31;
    const int dir   = (blk >> 7) & 1;
    const int pair  = blk >> 8;
    const float* P   = pose + b * 24 + pair * 12;   // fwd pose for pair0, inverse for pair1
    const float* raw = pair ? p2 : p1;
    const float* inA = pair ? p2in1 : p1in2;
    const int t = threadIdx.x;

    float m0 = P[0], m1 = P[1], m2 = P[2];
    float m3 = P[3], m4 = P[4], m5 = P[5];
    float m6 = P[6], m7 = P[7], m8 = P[8];
    float t0 = P[9], t1 = P[10], t2 = P[11];

    // stage Y set (1024 points, with |y|^2) into LDS
#pragma unroll
    for (int i = 0; i < 4; ++i) {
        int q = t + 256 * i;
        int gi = (b * NP + q) * 3;
        float x, y, z;
        if (dir == 0) { x = inA[gi]; y = inA[gi + 1]; z = inA[gi + 2]; }
        else {
            float rx = raw[gi], ry = raw[gi + 1], rz = raw[gi + 2];
            x = m0 * rx + m1 * ry + m2 * rz + t0;
            y = m3 * rx + m4 * ry + m5 * rz + t1;
            z = m6 * rx + m7 * ry + m8 * rz + t2;
        }
        ys[q] = make_float4(x, y, z, x * x + y * y + z * z);
    }
    __syncthreads();

    // this thread's X point
    int xi = chunk * 256 + t;
    int gx = (b * NP + xi) * 3;
    float x0, x1, x2;
    if (dir == 0) {
        float rx = raw[gx], ry = raw[gx + 1], rz = raw[gx + 2];
        x0 = m0 * rx + m1 * ry + m2 * rz + t0;
        x1 = m3 * rx + m4 * ry + m5 * rz + t1;
        x2 = m6 * rx + m7 * ry + m8 * rz + t2;
    } else { x0 = inA[gx]; x1 = inA[gx + 1]; x2 = inA[gx + 2]; }
    float sx = x0 * x0 + x1 * x1 + x2 * x2;

    float mn = 3.0e38f;
#pragma unroll 4
    for (int o = 0; o < NP; ++o) {
        float4 yv = ys[o];   // broadcast read, conflict-free
        float d = fmaf(-2.0f, x0 * yv.x + x1 * yv.y + x2 * yv.z, sx + yv.w);
        mn = fminf(mn, d);
    }
    mn = fmaxf(mn, 0.0f);    // clamp commutes with min

    float v = mn;
#pragma unroll
    for (int m = 1; m < 64; m <<= 1) v += __shfl_xor(v, m);
    if ((t & 63) == 0) atomicAdd(&acc[4], v);

    if (dir == 0) {          // Huber corr: A = inA (ys), P-set = transformed X
        float4 a = ys[xi];
        float s = 0.f;
        float d0 = fabsf(a.x - x0); s += (d0 > 0.1f) ? (d0 - 0.05f) : (d0 * d0 * 5.0f);
        float d1 = fabsf(a.y - x1); s += (d1 > 0.1f) ? (d1 - 0.05f) : (d1 * d1 * 5.0f);
        float d2 = fabsf(a.z - x2); s += (d2 > 0.1f) ? (d2 - 0.05f) : (d2 * d2 * 5.0f);
#pragma unroll
        for (int m = 1; m < 64; m <<= 1) s += __shfl_xor(s, m);
        if ((t & 63) == 0) atomicAdd(&acc[3], s);
    }
}

// ---------------- finalize ----------------
__global__ void k_final(const float* __restrict__ acc, const float* __restrict__ cosacc,
                        float* __restrict__ out) {
    if (threadIdx.x != 0) return;
    const float invBN = 1.0f / 32768.0f;
    float ent2 = 1e-4f * acc[0] * invBN;
    float ent1 = 1e-4f * (acc[2] - acc[1]) * invBN;
    float corr = acc[3] * invBN;
    float cham = acc[4] * invBN;
    float cosl = 0.f;
    for (int b = 0; b < 32; ++b) {
        float dot = cosacc[b];
        float na = fmaxf(sqrtf(cosacc[32 + b]), 1e-8f);
        float nb = fmaxf(sqrtf(cosacc[64 + b]), 1e-8f);
        cosl += 1.0f - dot / (na * nb);
    }
    cosl *= (1.0f / 32.0f);
    out[0] = cham + corr + ent2 + ent1 + cosl;
}

extern "C" void kernel_launch(void* const* d_in, const int* in_sizes, int n_in,
                              void* d_out, int out_size, void* d_ws, size_t ws_size,
                              hipStream_t stream) {
    const float* p1    = (const float*)d_in[0];
    const float* p2    = (const float*)d_in[1];
    const float* am1   = (const float*)d_in[2];
    const float* am2   = (const float*)d_in[3];
    const float* scale = (const float*)d_in[4];
    const float* rot   = (const float*)d_in[5];
    const float* tr    = (const float*)d_in[6];

    float* ws = (float*)d_ws;
    float* acc    = ws + OFF_ACC;
    float* cosacc = ws + OFF_COS;
    float* pose   = ws + OFF_POSE;
    float* p1in2  = ws + OFF_P1IN2;
    float* p2in1  = ws + OFF_P2IN1;
    float* invR   = ws + OFF_INVR;
    float* colP   = ws + OFF_COLP;

    k_pose<<<1, 64, 0, stream>>>(scale, rot, tr, ws);
    k_rows<<<2048, 256, 0, stream>>>(am1, am2, p1, p2, p1in2, p2in1, invR, acc);
    k_cols2<<<1024, 256, 0, stream>>>(am1, am2, invR, colP, cosacc);
    k_colred2<<<256, 256, 0, stream>>>(colP, acc);
    k_cham<<<512, 256, 0, stream>>>(p1, p2, p1in2, p2in1, pose, acc);
    k_final<<<1, 64, 0, stream>>>(acc, cosacc, (float*)d_out);
}